// Round 13
// baseline (19.183 us; speedup 1.0000x reference)
//
#include <hip/hip_runtime.h>

// HEAT layer with sorted timestamps — TWO dispatches, CH=128, QL=16, RG=16.
//   out[i] = P_inc[i] + eps*exp(beta*t_i) * Q_inc[i]   (+ duplicate-t fixup)
//   P_inc[i] = sum_{j<=i} h[j],  Q_inc[i] = sum_{j<=i} relu(h[j])*exp(-beta*t_j)
// Rows j>i with t[j]==t[i] contribute h[j] + eps*relu(h[j]) exactly.
//
// Lessons: r5/r6 — cross-XCD flag sync costs 40-250us (single-pass is dead).
// r7/r8 — redundant prefix pays an L2 tax unless it deletes a dispatch.
// r9/r10 — NT stores, hoisted loads. r11 — hv[16] spilled. r12 — slim
// 2-dispatch = 18.6us. r13: K2 barrier diet (3->2): per-thread expf for
// dec/epv straight from tt (VALU is 4% busy — free), rg sums no longer
// wait on other threads' dec writes.

namespace {
constexpr int S   = 8192;
constexpr int D   = 768;
constexpr int DV  = D / 4;       // 192 float4 per row
constexpr int CH  = 128;         // rows per chunk
constexpr int NC  = S / CH;      // 64 chunks
constexpr int QL  = 16;          // float4-columns per block
constexpr int NG  = DV / QL;     // 12 column groups
constexpr int RG  = 16;          // row-groups per block (256 thr)
constexpr int RR  = CH / RG;     // 8 rows per row-group
}

typedef float f4raw __attribute__((ext_vector_type(4)));

__device__ __forceinline__ float4 f4add(float4 a, float4 b) {
    return make_float4(a.x + b.x, a.y + b.y, a.z + b.z, a.w + b.w);
}
__device__ __forceinline__ void f4relu_fma(float4& acc, float4 h, float d) {
    acc.x += fmaxf(h.x, 0.f) * d;
    acc.y += fmaxf(h.y, 0.f) * d;
    acc.z += fmaxf(h.z, 0.f) * d;
    acc.w += fmaxf(h.w, 0.f) * d;
}

__global__ __launch_bounds__(256)
void heat_partials(const float* __restrict__ h, const float* __restrict__ t,
                   const float* __restrict__ betap,
                   float4* __restrict__ SP1, float4* __restrict__ SQ1) {
    const int tid = threadIdx.x, lane = tid & (QL - 1), r = tid / QL;
    const int c = blockIdx.x, g = blockIdx.y;
    const int q = g * QL + lane;
    __shared__ float tts[CH];
    __shared__ float4 rgP[RG][QL], rgQ[RG][QL];
    const float4* h4 = (const float4*)h;
    const int row0 = c * CH + r * RR;
    float4 hv[RR];
#pragma unroll
    for (int k = 0; k < RR; ++k) hv[k] = h4[(size_t)(row0 + k) * DV + q];
    if (tid < CH) tts[tid] = t[c * CH + tid];
    __syncthreads();
    const float beta = betap[0];
    float4 pp = {0, 0, 0, 0}, qq = {0, 0, 0, 0};
#pragma unroll
    for (int k = 0; k < RR; ++k) {
        pp = f4add(pp, hv[k]);
        f4relu_fma(qq, hv[k], expf(-beta * tts[r * RR + k]));
    }
    rgP[r][lane] = pp;
    rgQ[r][lane] = qq;
    __syncthreads();
    if (r == 0) {
        float4 sp = rgP[0][lane];
#pragma unroll
        for (int w = 1; w < RG; ++w) sp = f4add(sp, rgP[w][lane]);
        SP1[c * DV + q] = sp;
    } else if (r == 1) {
        float4 sq = rgQ[0][lane];
#pragma unroll
        for (int w = 1; w < RG; ++w) sq = f4add(sq, rgQ[w][lane]);
        SQ1[c * DV + q] = sq;
    }
}

__global__ __launch_bounds__(256)
void heat_out(const float* __restrict__ h, const float* __restrict__ t,
              const float* __restrict__ epsp, const float* __restrict__ betap,
              const float4* __restrict__ SP1, const float4* __restrict__ SQ1,
              float* __restrict__ out) {
    const int tid  = threadIdx.x;
    const int lane = tid & (QL - 1);
    const int r    = tid / QL;          // row-group 0..15
    const int c    = blockIdx.x;        // 128-row chunk
    const int g    = blockIdx.y;        // column group
    const int q    = g * QL + lane;
    const float eps = epsp[0], beta = betap[0];

    __shared__ float tt[CH + 1];
    __shared__ float4 rgP[RG][QL], rgQ[RG][QL];
    __shared__ float4 redP[RG][QL], redQ[RG][QL];

    const float4* h4   = (const float4*)h;
    float4*       out4 = (float4*)out;
    const int row0 = c * CH + r * RR;

    // Bulk h loads first; the small offset loads ride in their shadow.
    float4 hv[RR];
#pragma unroll
    for (int k = 0; k < RR; ++k) hv[k] = h4[(size_t)(row0 + k) * DV + q];

    // Per-block exclusive offset: <=63 predecessor partials striped over
    // 16 row-groups -> <=4 predicated load-pairs per thread (L2/IF-hot).
    const float4 z = {0, 0, 0, 0};
    float4 aP = z, aQ = z;
#pragma unroll
    for (int u = 0; u < NC / RG; ++u) {
        const int p = r + RG * u;
        if (p < c) {
            aP = f4add(aP, SP1[(size_t)p * DV + q]);
            aQ = f4add(aQ, SQ1[(size_t)p * DV + q]);
        }
    }

    if (tid <= CH) {
        int j = c * CH + tid;
        tt[tid] = (j < S) ? t[j] : 1e30f;   // sentinel past the end
    }
    __syncthreads();          // barrier 1: tt visible to all

    // Per-thread dec/epv for this thread's own 8 rows (no LDS round-trip).
    float dc[RR], ep[RR];
#pragma unroll
    for (int k = 0; k < RR; ++k) {
        const float tv = tt[r * RR + k];
        dc[k] = expf(-beta * tv);
        ep[k] = eps * expf(beta * tv);
    }

    // Within-chunk per-row-group sums.
    float4 pp = z, qq = z;
#pragma unroll
    for (int k = 0; k < RR; ++k) {
        pp = f4add(pp, hv[k]);
        f4relu_fma(qq, hv[k], dc[k]);
    }
    rgP[r][lane] = pp;
    rgQ[r][lane] = qq;
    redP[r][lane] = aP;
    redQ[r][lane] = aQ;
    __syncthreads();          // barrier 2: rg/red visible

    // po/qo = global offset (all 16 red slices) + within-chunk prefix.
    float4 po = redP[0][lane], qo = redQ[0][lane];
#pragma unroll
    for (int w = 1; w < RG; ++w) {
        po = f4add(po, redP[w][lane]);
        qo = f4add(qo, redQ[w][lane]);
    }
#pragma unroll
    for (int rr2 = 0; rr2 < RG - 1; ++rr2)
        if (rr2 < r) {
            po = f4add(po, rgP[rr2][lane]);
            qo = f4add(qo, rgQ[rr2][lane]);
        }

    // ---- emit out straight from registers (nontemporal stores) ----
#pragma unroll
    for (int k = 0; k < RR; ++k) {
        po = f4add(po, hv[k]);
        f4relu_fma(qo, hv[k], dc[k]);
        float4 o;
        o.x = po.x + ep[k] * qo.x;
        o.y = po.y + ep[k] * qo.y;
        o.z = po.z + ep[k] * qo.z;
        o.w = po.w + ep[k] * qo.w;
        const int lr = r * RR + k;
        if (tt[lr + 1] == tt[lr]) {          // rare: duplicate-timestamp run
            int j = row0 + k + 1;
            const float tcur = tt[lr];
            float tj = tt[lr + 1];
            while (tj == tcur) {
                float4 hj = h4[(size_t)j * DV + q];
                o.x += hj.x + eps * fmaxf(hj.x, 0.f);
                o.y += hj.y + eps * fmaxf(hj.y, 0.f);
                o.z += hj.z + eps * fmaxf(hj.z, 0.f);
                o.w += hj.w + eps * fmaxf(hj.w, 0.f);
                ++j;
                if (j >= S) break;
                const int lj = j - c * CH;
                tj = (lj <= CH) ? tt[lj] : t[j];
            }
        }
        __builtin_nontemporal_store(*(const f4raw*)&o,
            (f4raw*)(out4 + (size_t)(row0 + k) * DV + q));
    }
}

extern "C" void kernel_launch(void* const* d_in, const int* in_sizes, int n_in,
                              void* d_out, int out_size, void* d_ws, size_t ws_size,
                              hipStream_t stream) {
    const float* h    = (const float*)d_in[0];
    const float* t    = (const float*)d_in[1];
    const float* eps  = (const float*)d_in[2];
    const float* beta = (const float*)d_in[3];
    float* out = (float*)d_out;

    float4* SP1 = (float4*)d_ws;                 // NC*DV f4 = 196 KB
    float4* SQ1 = SP1 + (size_t)NC * DV;         // 196 KB

    heat_partials<<<dim3(NC, NG), 256, 0, stream>>>(h, t, beta, SP1, SQ1);
    heat_out<<<dim3(NC, NG), 256, 0, stream>>>(h, t, eps, beta, SP1, SQ1, out);
}

// Round 14
// 18.449 us; speedup vs baseline: 1.0398x; 1.0398x over previous
//
#include <hip/hip_runtime.h>

// HEAT layer with sorted timestamps — TWO dispatches, CH=128, QL=16, RG=16.
//   out[i] = P_inc[i] + eps*exp(beta*t_i) * Q_inc[i]   (+ duplicate-t fixup)
//   P_inc[i] = sum_{j<=i} h[j],  Q_inc[i] = sum_{j<=i} relu(h[j])*exp(-beta*t_j)
// Rows j>i with t[j]==t[i] contribute h[j] + eps*relu(h[j]) exactly.
//
// FINAL (= round-12 best, 18.57us): r13's barrier diet regressed (8x more
// per-thread expf on the critical path). Structure rationale:
//  - r2: cooperative launch silently no-ops -> no grid.sync available.
//  - r5/r6: intra-kernel cross-XCD flag sync costs 40-250us (agent-acquire
//    polls = L2 invalidates) -> single-pass scan is dead; the kernel
//    boundary is the cheapest device-wide barrier.
//  - r7/r8: redundant per-block prefix pays an L2-BW tax unless it deletes
//    a dispatch. r11: hv[16] + 16 in-flight offset loads spills.
//  - r9/r10: NT stores for out (never re-read), bulk h loads hoisted first.
// Floor arithmetic: 25MB cold h read + 25MB NT write (HBM) + 25MB IF-served
// h re-read + 1 dispatch gap ~= 15.5-16.5us; this lands ~18.6.

namespace {
constexpr int S   = 8192;
constexpr int D   = 768;
constexpr int DV  = D / 4;       // 192 float4 per row
constexpr int CH  = 128;         // rows per chunk
constexpr int NC  = S / CH;      // 64 chunks
constexpr int QL  = 16;          // float4-columns per block
constexpr int NG  = DV / QL;     // 12 column groups
constexpr int RG  = 16;          // row-groups per block (256 thr)
constexpr int RR  = CH / RG;     // 8 rows per row-group
}

typedef float f4raw __attribute__((ext_vector_type(4)));

__device__ __forceinline__ float4 f4add(float4 a, float4 b) {
    return make_float4(a.x + b.x, a.y + b.y, a.z + b.z, a.w + b.w);
}
__device__ __forceinline__ void f4relu_fma(float4& acc, float4 h, float d) {
    acc.x += fmaxf(h.x, 0.f) * d;
    acc.y += fmaxf(h.y, 0.f) * d;
    acc.z += fmaxf(h.z, 0.f) * d;
    acc.w += fmaxf(h.w, 0.f) * d;
}

__global__ __launch_bounds__(256)
void heat_partials(const float* __restrict__ h, const float* __restrict__ t,
                   const float* __restrict__ betap,
                   float4* __restrict__ SP1, float4* __restrict__ SQ1) {
    const int tid = threadIdx.x, lane = tid & (QL - 1), r = tid / QL;
    const int c = blockIdx.x, g = blockIdx.y;
    const int q = g * QL + lane;
    __shared__ float dec[CH];
    __shared__ float4 rgP[RG][QL], rgQ[RG][QL];
    const float4* h4 = (const float4*)h;
    const int row0 = c * CH + r * RR;
    float4 hv[RR];
#pragma unroll
    for (int k = 0; k < RR; ++k) hv[k] = h4[(size_t)(row0 + k) * DV + q];
    if (tid < CH) dec[tid] = expf(-betap[0] * t[c * CH + tid]);
    __syncthreads();
    float4 pp = {0, 0, 0, 0}, qq = {0, 0, 0, 0};
#pragma unroll
    for (int k = 0; k < RR; ++k) {
        pp = f4add(pp, hv[k]);
        f4relu_fma(qq, hv[k], dec[r * RR + k]);
    }
    rgP[r][lane] = pp;
    rgQ[r][lane] = qq;
    __syncthreads();
    if (r == 0) {
        float4 sp = rgP[0][lane];
#pragma unroll
        for (int w = 1; w < RG; ++w) sp = f4add(sp, rgP[w][lane]);
        SP1[c * DV + q] = sp;
    } else if (r == 1) {
        float4 sq = rgQ[0][lane];
#pragma unroll
        for (int w = 1; w < RG; ++w) sq = f4add(sq, rgQ[w][lane]);
        SQ1[c * DV + q] = sq;
    }
}

__global__ __launch_bounds__(256)
void heat_out(const float* __restrict__ h, const float* __restrict__ t,
              const float* __restrict__ epsp, const float* __restrict__ betap,
              const float4* __restrict__ SP1, const float4* __restrict__ SQ1,
              float* __restrict__ out) {
    const int tid  = threadIdx.x;
    const int lane = tid & (QL - 1);
    const int r    = tid / QL;          // row-group 0..15
    const int c    = blockIdx.x;        // 128-row chunk
    const int g    = blockIdx.y;        // column group
    const int q    = g * QL + lane;
    const float eps = epsp[0], beta = betap[0];

    __shared__ float tt[CH + 1];
    __shared__ float dec[CH], epv[CH];
    __shared__ float4 rgP[RG][QL], rgQ[RG][QL];
    __shared__ float4 redP[RG][QL], redQ[RG][QL];

    const float4* h4   = (const float4*)h;
    float4*       out4 = (float4*)out;
    const int row0 = c * CH + r * RR;

    // Bulk h loads first; the small offset loads ride in their shadow.
    float4 hv[RR];
#pragma unroll
    for (int k = 0; k < RR; ++k) hv[k] = h4[(size_t)(row0 + k) * DV + q];

    // Per-block exclusive offset: <=63 predecessor partials striped over
    // 16 row-groups -> <=4 predicated load-pairs per thread (L2/IF-hot).
    const float4 z = {0, 0, 0, 0};
    float4 aP = z, aQ = z;
#pragma unroll
    for (int u = 0; u < NC / RG; ++u) {
        const int p = r + RG * u;
        if (p < c) {
            aP = f4add(aP, SP1[(size_t)p * DV + q]);
            aQ = f4add(aQ, SQ1[(size_t)p * DV + q]);
        }
    }

    if (tid <= CH) {
        int j = c * CH + tid;
        tt[tid] = (j < S) ? t[j] : 1e30f;   // sentinel past the end
    }
    __syncthreads();
    if (tid < CH) {
        float tv = tt[tid];
        dec[tid] = expf(-beta * tv);
        epv[tid] = eps * expf(beta * tv);
    }
    __syncthreads();

    // Within-chunk per-row-group sums.
    float4 pp = z, qq = z;
#pragma unroll
    for (int k = 0; k < RR; ++k) {
        pp = f4add(pp, hv[k]);
        f4relu_fma(qq, hv[k], dec[r * RR + k]);
    }
    rgP[r][lane] = pp;
    rgQ[r][lane] = qq;
    redP[r][lane] = aP;
    redQ[r][lane] = aQ;
    __syncthreads();

    // po/qo = global offset (all 16 red slices) + within-chunk prefix.
    float4 po = redP[0][lane], qo = redQ[0][lane];
#pragma unroll
    for (int w = 1; w < RG; ++w) {
        po = f4add(po, redP[w][lane]);
        qo = f4add(qo, redQ[w][lane]);
    }
#pragma unroll
    for (int rr2 = 0; rr2 < RG - 1; ++rr2)
        if (rr2 < r) {
            po = f4add(po, rgP[rr2][lane]);
            qo = f4add(qo, rgQ[rr2][lane]);
        }

    // ---- emit out straight from registers (nontemporal stores) ----
#pragma unroll
    for (int k = 0; k < RR; ++k) {
        po = f4add(po, hv[k]);
        f4relu_fma(qo, hv[k], dec[r * RR + k]);
        const float ep = epv[r * RR + k];
        float4 o;
        o.x = po.x + ep * qo.x;
        o.y = po.y + ep * qo.y;
        o.z = po.z + ep * qo.z;
        o.w = po.w + ep * qo.w;
        const int lr = r * RR + k;
        if (tt[lr + 1] == tt[lr]) {          // rare: duplicate-timestamp run
            int j = row0 + k + 1;
            const float tcur = tt[lr];
            float tj = tt[lr + 1];
            while (tj == tcur) {
                float4 hj = h4[(size_t)j * DV + q];
                o.x += hj.x + eps * fmaxf(hj.x, 0.f);
                o.y += hj.y + eps * fmaxf(hj.y, 0.f);
                o.z += hj.z + eps * fmaxf(hj.z, 0.f);
                o.w += hj.w + eps * fmaxf(hj.w, 0.f);
                ++j;
                if (j >= S) break;
                const int lj = j - c * CH;
                tj = (lj <= CH) ? tt[lj] : t[j];
            }
        }
        __builtin_nontemporal_store(*(const f4raw*)&o,
            (f4raw*)(out4 + (size_t)(row0 + k) * DV + q));
    }
}

extern "C" void kernel_launch(void* const* d_in, const int* in_sizes, int n_in,
                              void* d_out, int out_size, void* d_ws, size_t ws_size,
                              hipStream_t stream) {
    const float* h    = (const float*)d_in[0];
    const float* t    = (const float*)d_in[1];
    const float* eps  = (const float*)d_in[2];
    const float* beta = (const float*)d_in[3];
    float* out = (float*)d_out;

    float4* SP1 = (float4*)d_ws;                 // NC*DV f4 = 196 KB
    float4* SQ1 = SP1 + (size_t)NC * DV;         // 196 KB

    heat_partials<<<dim3(NC, NG), 256, 0, stream>>>(h, t, beta, SP1, SQ1);
    heat_out<<<dim3(NC, NG), 256, 0, stream>>>(h, t, eps, beta, SP1, SQ1, out);
}